// Round 18
// baseline (468.733 us; speedup 1.0000x reference)
//
#include <hip/hip_runtime.h>

// out[b,o] = sum_h W2[o,h]*leaky(h) + b2[o],  h = W1[o]·x[b] + b1[o]
// leaky(t) = 0.6t + 0.4|t|
//   out[b,o] = 0.6(v[o]·x[b]) + c0[o] + sum_h (0.4 W2[o,h])|h|
// R19 = R18 (stage1 mfma16 K=16 exact, b1 rides f32-C; stage2 = 4 v_fma_f32
// with free |.|; exact-f32 linear init; weights LDS-resident) + the fix for
// R18's hoist-spill: ct-loop fully unrolled (static LDS offsets, R13's fast
// property) with __builtin_amdgcn_sched_barrier(0) every 4th ct — bounds the
// scheduler's hoist window to <=4 iters (~85 VGPR live max, cap 128, cannot
// spill). R18 (no fence): scheduler hoisted 32 iters of LDS reads -> 320 VGPR
// live -> 870MB scratch writes, 468us. R14/R15/R16/R18 were ALL regalloc
// pathologies, never the algorithm.

#define H_DIM 512

typedef _Float16 f16x4 __attribute__((ext_vector_type(4)));
typedef __fp16   h16x2 __attribute__((ext_vector_type(2)));   // cvt_pkrtz native
typedef float    f32x4 __attribute__((ext_vector_type(4)));
typedef int      i32x2 __attribute__((ext_vector_type(2)));

// 512 blocks x 512 thr (8 waves), 2 blocks/CU ((512,2): 2nd arg acts as
// blocks/CU; cap-128 verified R13/R15). o = blk&15, grp = blk>>4 (32).
// Wave w: 8 tiles of 16 batch rows, tile0 = grp*64 + w*8.
__global__ __launch_bounds__(512, 2) void mlp_fused(
    const float* __restrict__ x, const float* __restrict__ W1,
    const float* __restrict__ b1, const float* __restrict__ W2,
    const float* __restrict__ b2, float* __restrict__ out) {
    __shared__ f16x4 sm_a1[2048];     // [ct][lane] W1 frags      16 KiB
    __shared__ f32x4 sm_w2c[128];     // [ct][kg] 0.4*W2           2 KiB
    __shared__ f32x4 sm_b1c[128];     // [ct][kg] b1               2 KiB
    __shared__ float red[512];
    __shared__ float v_sm[16];
    __shared__ float c_sm;

    const int tid = threadIdx.x;
    const int o   = blockIdx.x & 15;
    const int grp = blockIdx.x >> 4;
    const float* W1o = W1 + (size_t)o * H_DIM * 16;
    const float* W2o = W2 + (size_t)o * H_DIM;
    const float* b1o = b1 + (size_t)o * H_DIM;

    // ---- phase A: stage fragments ----
#pragma unroll
    for (int i = 0; i < 4; ++i) {
        const int e = tid + 512 * i;          // 0..2047 = [ct][lane]
        const int l = e & 63, ct = e >> 6;
        const int row = l & 15, kg = l >> 4;
        const f32x4 wv = *reinterpret_cast<const f32x4*>(
            W1o + (size_t)(ct * 16 + row) * 16 + kg * 4);
        h16x2 q0 = __builtin_amdgcn_cvt_pkrtz(wv[0], wv[1]);
        h16x2 q1 = __builtin_amdgcn_cvt_pkrtz(wv[2], wv[3]);
        i32x2 vi; vi[0] = __builtin_bit_cast(int, q0); vi[1] = __builtin_bit_cast(int, q1);
        sm_a1[e] = __builtin_bit_cast(f16x4, vi);
    }
    if (tid < 128) {                          // [ct][kg]
        const int kg = tid & 3, ct = tid >> 2;
        f32x4 wv, bv;
#pragma unroll
        for (int r = 0; r < 4; ++r) {
            wv[r] = 0.4f * W2o[ct * 16 + kg * 4 + r];
            bv[r] = b1o[ct * 16 + kg * 4 + r];
        }
        sm_w2c[tid] = wv;
        sm_b1c[tid] = bv;
    }
    {   // v[i] = 0.6 sum_h W2[h] W1[h,i]
        const int i = tid & 15, hc = tid >> 4;     // 32 chunks x 16 h
        float a = 0.f;
#pragma unroll
        for (int hh = 0; hh < 16; ++hh) {
            const int h = hc * 16 + hh;
            a = fmaf(W2o[h], W1o[(size_t)h * 16 + i], a);
        }
        red[tid] = a;
    }
    __syncthreads();
    if (tid < 16) {
        float s = 0.f;
#pragma unroll
        for (int k = 0; k < 32; ++k) s += red[tid + 16 * k];
        v_sm[tid] = 0.6f * s;
    }
    const float cp = W2o[tid] * b1o[tid];
    __syncthreads();
    red[tid] = cp;
    __syncthreads();
    if (tid < 64) {
        float s = 0.f;
#pragma unroll
        for (int k = 0; k < 8; ++k) s += red[tid + 64 * k];
#pragma unroll
        for (int m = 1; m <= 32; m <<= 1) s += __shfl_xor(s, m, 64);
        if (tid == 0) c_sm = 0.6f * s + b2[o];
    }
    __syncthreads();

    // ---- phase B ----
    const int lane = tid & 63, w = tid >> 6;
    const int col = lane & 15, kg = lane >> 4;
    const int tile0 = grp * 64 + w * 8;

    const f32x4 vr = *reinterpret_cast<const f32x4*>(&v_sm[kg * 4]);
    const float c0 = c_sm;

    // x load + exact-f32 linear init + f16 fold
    f16x4 xf[8];
    float nl[8];
#pragma unroll
    for (int j = 0; j < 8; ++j) {
        const f32x4 xv = *reinterpret_cast<const f32x4*>(
            x + (size_t)((tile0 + j) * 16 + col) * 16 + kg * 4);
        float lp = xv[0] * vr[0];
        lp = fmaf(xv[1], vr[1], lp);
        lp = fmaf(xv[2], vr[2], lp);
        lp = fmaf(xv[3], vr[3], lp);
        nl[j] = lp;
        h16x2 q0 = __builtin_amdgcn_cvt_pkrtz(xv[0], xv[1]);
        h16x2 q1 = __builtin_amdgcn_cvt_pkrtz(xv[2], xv[3]);
        i32x2 xi; xi[0] = __builtin_bit_cast(int, q0); xi[1] = __builtin_bit_cast(int, q1);
        xf[j] = __builtin_bit_cast(f16x4, xi);
    }

#pragma unroll
    for (int ct = 0; ct < 32; ++ct) {
        if ((ct & 3) == 0) __builtin_amdgcn_sched_barrier(0);  // fence hoisting
        const f16x4 A1 = sm_a1[ct * 64 + lane];   // static offset (unrolled)
        const f32x4 wv = sm_w2c[ct * 4 + kg];     // broadcast (kg-only addr)
        const f32x4 bv = sm_b1c[ct * 4 + kg];
#pragma unroll
        for (int j = 0; j < 8; ++j) {
            // stage1: d[r] = h[ct*16 + kg*4 + r] for b=col (bias via C)
            const f32x4 d = __builtin_amdgcn_mfma_f32_16x16x16f16(A1, xf[j], bv, 0, 0, 0);
            // stage2: 4 FMAs, |d| is a free VOP3 source modifier
            nl[j] = fmaf(wv[0], fabsf(d[0]), nl[j]);
            nl[j] = fmaf(wv[1], fabsf(d[1]), nl[j]);
            nl[j] = fmaf(wv[2], fabsf(d[2]), nl[j]);
            nl[j] = fmaf(wv[3], fabsf(d[3]), nl[j]);
        }
    }

    // reduce over kg (lanes differing in bits 4-5) and store
#pragma unroll
    for (int j = 0; j < 8; ++j) {
        float s = nl[j];
        s += __shfl_xor(s, 16, 64);
        s += __shfl_xor(s, 32, 64);
        if (lane < 16)
            out[(size_t)((tile0 + j) * 16 + lane) * 16 + o] = s + c0;
    }
}

extern "C" void kernel_launch(void* const* d_in, const int* in_sizes, int n_in,
                              void* d_out, int out_size, void* d_ws, size_t ws_size,
                              hipStream_t stream) {
    const float* x  = (const float*)d_in[0];
    const float* W1 = (const float*)d_in[1];
    const float* b1 = (const float*)d_in[2];
    const float* W2 = (const float*)d_in[3];
    const float* b2 = (const float*)d_in[4];
    float* out = (float*)d_out;

    mlp_fused<<<512, 512, 0, stream>>>(x, W1, b1, W2, b2, out);
}

// Round 19
// 26.537 us; speedup vs baseline: 17.6636x; 17.6636x over previous
//
#include <hip/hip_runtime.h>

// out[b,o] = sum_h W2[o,h]*leaky(h) + b2[o],  h = W1[o]·x[b] + b1[o]
// leaky(t) = 0.6t + 0.4|t|
//   out[b,o] = 0.6(v[o]·x[b] + c0[o]) + b2[o] + sum_h (0.4 W2[o,h])|h|
// R20 = R13 (the proven 27.7us structure: fused, stage1 mfma16 K=16 exact
// w/ b1-as-C, stage2 mfma32 w/ verified k->h perm, unroll-2 p-loop, (512,2))
// with per-block work DOUBLED: 256 blocks (1/CU), outer half-loop covers
// 2x64 tiles. Amortizes phase-A staging 2x, halves WG count. Register
// structure byte-identical to R13's phase B (arrays scoped inside half-loop;
// half only in scalar addressing) -> no spill risk. R14/15/16/18/19 were all
// regalloc pathologies; this round deliberately changes NOTHING in the loop.

#define B_DIM 32768
#define I_DIM 16
#define O_DIM 16
#define H_DIM 512

typedef _Float16 f16x4 __attribute__((ext_vector_type(4)));
typedef _Float16 f16x8 __attribute__((ext_vector_type(8)));
typedef __fp16   h16x2 __attribute__((ext_vector_type(2)));   // cvt_pkrtz native
typedef float    f32x4 __attribute__((ext_vector_type(4)));
typedef int      i32x2 __attribute__((ext_vector_type(2)));
typedef int      i32x4 __attribute__((ext_vector_type(4)));

// 256 blocks x 512 thr (8 waves), 1 block/CU. o = blk&15, grp = blk>>4 (16).
// Block covers 128 b-tiles in two halves of 64; wave w: 8 tiles per half.
__global__ __launch_bounds__(512, 2) void mlp_fused(
    const float* __restrict__ x, const float* __restrict__ W1,
    const float* __restrict__ b1, const float* __restrict__ W2,
    const float* __restrict__ b2, float* __restrict__ out) {
    __shared__ f16x8 sm_a1[1024];     // [p][lane] stage1-A pairs   16 KiB
    __shared__ f16x8 sm_w2[1024];     // [p][lane] stage2-B (0.4x)  16 KiB
    __shared__ float sm_b1[512];      //  2 KiB
    __shared__ float red[512];        //  2 KiB scratch
    __shared__ float v_sm[16];
    __shared__ float c_sm;

    const int tid = threadIdx.x;
    const int o   = blockIdx.x & 15;
    const int grp = blockIdx.x >> 4;
    const float* W1o = W1 + (size_t)o * H_DIM * I_DIM;
    const float* W2o = W2 + (size_t)o * H_DIM;
    const float* b1o = b1 + (size_t)o * H_DIM;

    // ---- phase A: stage fragments (identical to R13) ----
#pragma unroll
    for (int i = 0; i < 2; ++i) {
        const int e = tid + 512 * i;          // 0..1023 = [p][lane]
        const int l = e & 63, p = e >> 6;
        const int row = l & 15, kg = l >> 4;
        // stage1-A pair: ct=2p (elems 0-3), ct=2p+1 (elems 4-7)
        const float* a_base = W1o + ((size_t)(2 * p * 16 + row) * I_DIM + kg * 4);
        const f32x4 a0 = *reinterpret_cast<const f32x4*>(a_base);
        const f32x4 a1v = *reinterpret_cast<const f32x4*>(a_base + 16 * I_DIM);
        f16x8 va;
#pragma unroll
        for (int j = 0; j < 4; ++j) { va[j] = (_Float16)a0[j]; va[4 + j] = (_Float16)a1v[j]; }
        sm_a1[e] = va;
        // stage2-B: k=kg*8+j -> h = p*32 + ((j>>2)&1)*16 + kg*4 + (j&3)
        const float* w_base = W2o + p * 32 + kg * 4;
        const f32x4 w0 = *reinterpret_cast<const f32x4*>(w_base);
        const f32x4 w1v = *reinterpret_cast<const f32x4*>(w_base + 16);
        f16x8 vw;
#pragma unroll
        for (int j = 0; j < 4; ++j) {
            vw[j]     = (_Float16)(0.4f * w0[j]);
            vw[4 + j] = (_Float16)(0.4f * w1v[j]);
        }
        sm_w2[e] = vw;
    }
    sm_b1[tid] = b1o[tid];

    // ---- phase A2: v[i] = 0.6 sum_h W2[h]W1[h,i]; c0 = 0.6 sum W2 b1 + b2 ----
    {
        const int i = tid & 15, hc = tid >> 4;     // 32 chunks x 16 h
        float acc = 0.f;
#pragma unroll
        for (int hh = 0; hh < 16; ++hh) {
            const int h = hc * 16 + hh;
            acc = fmaf(W2o[h], W1o[(size_t)h * I_DIM + i], acc);
        }
        red[tid] = acc;
    }
    __syncthreads();
    if (tid < 16) {
        float s = 0.f;
#pragma unroll
        for (int k = 0; k < 32; ++k) s += red[tid + 16 * k];
        v_sm[tid] = 0.6f * s;
    }
    float cpart = W2o[tid] * b1o[tid];
    __syncthreads();
    red[tid] = cpart;
    __syncthreads();
    if (tid < 64) {
        float s = 0.f;
#pragma unroll
        for (int k = 0; k < 8; ++k) s += red[tid + 64 * k];
#pragma unroll
        for (int m = 1; m <= 32; m <<= 1) s += __shfl_xor(s, m, 64);
        if (tid == 0) c_sm = 0.6f * s + b2[o];
    }
    __syncthreads();

    // ---- phase B (R13 body, x2 halves) ----
    const int lane = tid & 63, w = tid >> 6;
    const int col = lane & 15, kg = lane >> 4;

    for (int half = 0; half < 2; ++half) {
        const int tile0 = grp * 128 + half * 64 + w * 8;

        f16x4 xf[8];
#pragma unroll
        for (int t = 0; t < 8; ++t) {
            const f32x4 xv = *reinterpret_cast<const f32x4*>(
                x + (size_t)((tile0 + t) * 16 + col) * I_DIM + kg * 4);
            h16x2 q0 = __builtin_amdgcn_cvt_pkrtz(xv[0], xv[1]);
            h16x2 q1 = __builtin_amdgcn_cvt_pkrtz(xv[2], xv[3]);
            i32x2 xi; xi[0] = __builtin_bit_cast(int, q0); xi[1] = __builtin_bit_cast(int, q1);
            xf[t] = __builtin_bit_cast(f16x4, xi);
        }

        f16x4 vlf;
#pragma unroll
        for (int j = 0; j < 4; ++j) vlf[j] = (_Float16)v_sm[kg * 4 + j];
        const float c0 = c_sm;
        const f32x4 linC = {c0, c0, c0, c0};

        f32x4 acc[8];
#pragma unroll
        for (int t = 0; t < 8; ++t)
            acc[t] = __builtin_amdgcn_mfma_f32_16x16x16f16(xf[t], vlf, linC, 0, 0, 0);

#pragma unroll 2
        for (int p = 0; p < 16; ++p) {
            const f16x8 a1pair = sm_a1[p * 64 + lane];
            const f16x4 A1a = __builtin_shufflevector(a1pair, a1pair, 0, 1, 2, 3);
            const f16x4 A1b = __builtin_shufflevector(a1pair, a1pair, 4, 5, 6, 7);
            const f16x8 W2f = sm_w2[p * 64 + lane];
            const f32x4 bC0 = *reinterpret_cast<const f32x4*>(&sm_b1[p * 32 + kg * 4]);
            const f32x4 bC1 = *reinterpret_cast<const f32x4*>(&sm_b1[p * 32 + 16 + kg * 4]);
#pragma unroll
            for (int t = 0; t < 8; ++t) {
                f32x4 d0 = __builtin_amdgcn_mfma_f32_16x16x16f16(A1a, xf[t], bC0, 0, 0, 0);
                f32x4 d1 = __builtin_amdgcn_mfma_f32_16x16x16f16(A1b, xf[t], bC1, 0, 0, 0);
                h16x2 p0 = __builtin_amdgcn_cvt_pkrtz(fabsf(d0[0]), fabsf(d0[1]));
                h16x2 p1 = __builtin_amdgcn_cvt_pkrtz(fabsf(d0[2]), fabsf(d0[3]));
                h16x2 p2 = __builtin_amdgcn_cvt_pkrtz(fabsf(d1[0]), fabsf(d1[1]));
                h16x2 p3 = __builtin_amdgcn_cvt_pkrtz(fabsf(d1[2]), fabsf(d1[3]));
                i32x4 ai;
                ai[0] = __builtin_bit_cast(int, p0); ai[1] = __builtin_bit_cast(int, p1);
                ai[2] = __builtin_bit_cast(int, p2); ai[3] = __builtin_bit_cast(int, p3);
                f16x8 A2 = __builtin_bit_cast(f16x8, ai);
                acc[t] = __builtin_amdgcn_mfma_f32_16x16x32_f16(A2, W2f, acc[t], 0, 0, 0);
            }
        }

        // acc[t][r]: b_local = kg*4 + r (all 16 cols identical).
        if (col < 4) {
#pragma unroll
            for (int t = 0; t < 8; ++t) {
                float v = (col == 0) ? acc[t][0] : (col == 1) ? acc[t][1]
                        : (col == 2) ? acc[t][2] : acc[t][3];
                out[(size_t)((tile0 + t) * 16 + kg * 4 + col) * O_DIM + o] = v;
            }
        }
    }
}

extern "C" void kernel_launch(void* const* d_in, const int* in_sizes, int n_in,
                              void* d_out, int out_size, void* d_ws, size_t ws_size,
                              hipStream_t stream) {
    const float* x  = (const float*)d_in[0];
    const float* W1 = (const float*)d_in[1];
    const float* b1 = (const float*)d_in[2];
    const float* W2 = (const float*)d_in[3];
    const float* b2 = (const float*)d_in[4];
    float* out = (float*)d_out;

    mlp_fused<<<256, 512, 0, stream>>>(x, W1, b1, W2, b2, out);
}

// Round 20
// 26.072 us; speedup vs baseline: 17.9785x; 1.0178x over previous
//
#include <hip/hip_runtime.h>

// out[b,o] = sum_h W2[o,h]*leaky(h) + b2[o],  h = W1[o]·x[b] + b1[o]
// leaky(t) = 0.6t + 0.4|t|
//   out[b,o] = 0.6(v[o]·x[b] + c0[o]) + b2[o] + sum_h (0.4 W2[o,h])|h|
// R21 = R20 (26.5us: fused, 256 blk x 512 thr, 1/CU, 128 tiles/block in 2
// halves; stage1 mfma16 K=16 exact w/ b1-as-C, stage2 mfma32 verified k->h
// perm, unroll-2 p-loop) with phase A slimmed:
//  - v[i]=sum_h W2[h]W1[h,i] fused into the staging loop (W1 loaded once,
//    not re-read by a separate 16-iter pass),
//  - 3 barriers -> 2 (v + c0 reduced together by wave 0),
//  - half-0 x loads hoisted above the barriers (HBM latency hides under A).
// Phase B byte-identical to R20 — no regalloc exposure (R14-R19 lesson).

#define B_DIM 32768
#define I_DIM 16
#define O_DIM 16
#define H_DIM 512

typedef _Float16 f16x4 __attribute__((ext_vector_type(4)));
typedef _Float16 f16x8 __attribute__((ext_vector_type(8)));
typedef __fp16   h16x2 __attribute__((ext_vector_type(2)));   // cvt_pkrtz native
typedef float    f32x4 __attribute__((ext_vector_type(4)));
typedef int      i32x2 __attribute__((ext_vector_type(2)));
typedef int      i32x4 __attribute__((ext_vector_type(4)));

// 256 blocks x 512 thr (8 waves), 1 block/CU. o = blk&15, grp = blk>>4 (16).
// Block covers 128 b-tiles in two halves of 64; wave w: 8 tiles per half.
__global__ __launch_bounds__(512, 2) void mlp_fused(
    const float* __restrict__ x, const float* __restrict__ W1,
    const float* __restrict__ b1, const float* __restrict__ W2,
    const float* __restrict__ b2, float* __restrict__ out) {
    __shared__ f16x8 sm_a1[1024];     // [p][lane] stage1-A pairs   16 KiB
    __shared__ f16x8 sm_w2[1024];     // [p][lane] stage2-B (0.4x)  16 KiB
    __shared__ float sm_b1[512];      //  2 KiB
    __shared__ f32x4 red4[512];       //  8 KiB (v partials)
    __shared__ float red[512];        //  2 KiB (c0 partials)
    __shared__ float v_sm[16];
    __shared__ float c_sm;

    const int tid = threadIdx.x;
    const int o   = blockIdx.x & 15;
    const int grp = blockIdx.x >> 4;
    const float* W1o = W1 + (size_t)o * H_DIM * I_DIM;
    const float* W2o = W2 + (size_t)o * H_DIM;
    const float* b1o = b1 + (size_t)o * H_DIM;

    const int lane = tid & 63, w = tid >> 6;
    const int col = lane & 15, kg = lane >> 4;

    // ---- phase A: stage fragments + fused v-partials ----
    f32x4 vpart = {0.f, 0.f, 0.f, 0.f};
#pragma unroll
    for (int i = 0; i < 2; ++i) {
        const int e = tid + 512 * i;          // 0..1023 = [p][lane]
        const int l = e & 63, p = e >> 6;
        const int row = l & 15, kgs = l >> 4;
        // stage1-A pair: rows h0=2p*16+row, h1=h0+16; cols kgs*4..+4
        const float* a_base = W1o + ((size_t)(2 * p * 16 + row) * I_DIM + kgs * 4);
        const f32x4 a0 = *reinterpret_cast<const f32x4*>(a_base);
        const f32x4 a1v = *reinterpret_cast<const f32x4*>(a_base + 16 * I_DIM);
        f16x8 va;
#pragma unroll
        for (int j = 0; j < 4; ++j) { va[j] = (_Float16)a0[j]; va[4 + j] = (_Float16)a1v[j]; }
        sm_a1[e] = va;
        // fused v-partial: vpart[j] += W2[h0]*W1[h0,kgs*4+j] + W2[h1]*W1[h1,..]
        const float w2a = W2o[2 * p * 16 + row];
        const float w2b = W2o[2 * p * 16 + 16 + row];
#pragma unroll
        for (int j = 0; j < 4; ++j)
            vpart[j] = fmaf(w2b, a1v[j], fmaf(w2a, a0[j], vpart[j]));
        // stage2-B: k=kgs*8+j -> h = p*32 + ((j>>2)&1)*16 + kgs*4 + (j&3)
        const float* w_base = W2o + p * 32 + kgs * 4;
        const f32x4 w0 = *reinterpret_cast<const f32x4*>(w_base);
        const f32x4 w1v = *reinterpret_cast<const f32x4*>(w_base + 16);
        f16x8 vw;
#pragma unroll
        for (int j = 0; j < 4; ++j) {
            vw[j]     = (_Float16)(0.4f * w0[j]);
            vw[4 + j] = (_Float16)(0.4f * w1v[j]);
        }
        sm_w2[e] = vw;
    }
    {
        const float b1v = b1o[tid];
        sm_b1[tid] = b1v;
        red[tid]   = W2o[tid] * b1v;          // c0 partial
        red4[tid]  = vpart;                   // v partial (cols kg*4..+4)
    }

    // hoist half-0 x loads: HBM latency hides under phase-A reduce
    f16x4 xf0[8];
    {
        const int tile0 = grp * 128 + w * 8;
#pragma unroll
        for (int t = 0; t < 8; ++t) {
            const f32x4 xv = *reinterpret_cast<const f32x4*>(
                x + (size_t)((tile0 + t) * 16 + col) * I_DIM + kg * 4);
            h16x2 q0 = __builtin_amdgcn_cvt_pkrtz(xv[0], xv[1]);
            h16x2 q1 = __builtin_amdgcn_cvt_pkrtz(xv[2], xv[3]);
            i32x2 xi; xi[0] = __builtin_bit_cast(int, q0); xi[1] = __builtin_bit_cast(int, q1);
            xf0[t] = __builtin_bit_cast(f16x4, xi);
        }
    }
    __syncthreads();

    // wave 0: reduce v (f32x4 per kg-group) and c0 together
    if (tid < 64) {
        f32x4 s = red4[tid];
#pragma unroll
        for (int k = 1; k < 8; ++k) s += red4[tid + 64 * k];
#pragma unroll
        for (int m = 1; m <= 8; m <<= 1) {
#pragma unroll
            for (int c = 0; c < 4; ++c) s[c] += __shfl_xor(s[c], m, 64);
        }
        if ((tid & 15) == 0) {
            const int kgw = tid >> 4;
#pragma unroll
            for (int j = 0; j < 4; ++j) v_sm[kgw * 4 + j] = 0.6f * s[j];
        }
        float cs = 0.f;
#pragma unroll
        for (int k = 0; k < 8; ++k) cs += red[tid + 64 * k];
#pragma unroll
        for (int m = 1; m <= 32; m <<= 1) cs += __shfl_xor(cs, m, 64);
        if (tid == 0) c_sm = 0.6f * cs + b2[o];
    }
    __syncthreads();

    // ---- phase B (R20 body, verbatim; half 0 uses hoisted xf0) ----
    for (int half = 0; half < 2; ++half) {
        const int tile0 = grp * 128 + half * 64 + w * 8;

        f16x4 xf[8];
        if (half == 0) {
#pragma unroll
            for (int t = 0; t < 8; ++t) xf[t] = xf0[t];
        } else {
#pragma unroll
            for (int t = 0; t < 8; ++t) {
                const f32x4 xv = *reinterpret_cast<const f32x4*>(
                    x + (size_t)((tile0 + t) * 16 + col) * I_DIM + kg * 4);
                h16x2 q0 = __builtin_amdgcn_cvt_pkrtz(xv[0], xv[1]);
                h16x2 q1 = __builtin_amdgcn_cvt_pkrtz(xv[2], xv[3]);
                i32x2 xi; xi[0] = __builtin_bit_cast(int, q0); xi[1] = __builtin_bit_cast(int, q1);
                xf[t] = __builtin_bit_cast(f16x4, xi);
            }
        }

        f16x4 vlf;
#pragma unroll
        for (int j = 0; j < 4; ++j) vlf[j] = (_Float16)v_sm[kg * 4 + j];
        const float c0 = c_sm;
        const f32x4 linC = {c0, c0, c0, c0};

        f32x4 acc[8];
#pragma unroll
        for (int t = 0; t < 8; ++t)
            acc[t] = __builtin_amdgcn_mfma_f32_16x16x16f16(xf[t], vlf, linC, 0, 0, 0);

#pragma unroll 2
        for (int p = 0; p < 16; ++p) {
            const f16x8 a1pair = sm_a1[p * 64 + lane];
            const f16x4 A1a = __builtin_shufflevector(a1pair, a1pair, 0, 1, 2, 3);
            const f16x4 A1b = __builtin_shufflevector(a1pair, a1pair, 4, 5, 6, 7);
            const f16x8 W2f = sm_w2[p * 64 + lane];
            const f32x4 bC0 = *reinterpret_cast<const f32x4*>(&sm_b1[p * 32 + kg * 4]);
            const f32x4 bC1 = *reinterpret_cast<const f32x4*>(&sm_b1[p * 32 + 16 + kg * 4]);
#pragma unroll
            for (int t = 0; t < 8; ++t) {
                f32x4 d0 = __builtin_amdgcn_mfma_f32_16x16x16f16(A1a, xf[t], bC0, 0, 0, 0);
                f32x4 d1 = __builtin_amdgcn_mfma_f32_16x16x16f16(A1b, xf[t], bC1, 0, 0, 0);
                h16x2 p0 = __builtin_amdgcn_cvt_pkrtz(fabsf(d0[0]), fabsf(d0[1]));
                h16x2 p1 = __builtin_amdgcn_cvt_pkrtz(fabsf(d0[2]), fabsf(d0[3]));
                h16x2 p2 = __builtin_amdgcn_cvt_pkrtz(fabsf(d1[0]), fabsf(d1[1]));
                h16x2 p3 = __builtin_amdgcn_cvt_pkrtz(fabsf(d1[2]), fabsf(d1[3]));
                i32x4 ai;
                ai[0] = __builtin_bit_cast(int, p0); ai[1] = __builtin_bit_cast(int, p1);
                ai[2] = __builtin_bit_cast(int, p2); ai[3] = __builtin_bit_cast(int, p3);
                f16x8 A2 = __builtin_bit_cast(f16x8, ai);
                acc[t] = __builtin_amdgcn_mfma_f32_16x16x32_f16(A2, W2f, acc[t], 0, 0, 0);
            }
        }

        // acc[t][r]: b_local = kg*4 + r (all 16 cols identical).
        if (col < 4) {
#pragma unroll
            for (int t = 0; t < 8; ++t) {
                float v = (col == 0) ? acc[t][0] : (col == 1) ? acc[t][1]
                        : (col == 2) ? acc[t][2] : acc[t][3];
                out[(size_t)((tile0 + t) * 16 + kg * 4 + col) * O_DIM + o] = v;
            }
        }
    }
}

extern "C" void kernel_launch(void* const* d_in, const int* in_sizes, int n_in,
                              void* d_out, int out_size, void* d_ws, size_t ws_size,
                              hipStream_t stream) {
    const float* x  = (const float*)d_in[0];
    const float* W1 = (const float*)d_in[1];
    const float* b1 = (const float*)d_in[2];
    const float* W2 = (const float*)d_in[3];
    const float* b2 = (const float*)d_in[4];
    float* out = (float*)d_out;

    mlp_fused<<<256, 512, 0, stream>>>(x, W1, b1, W2, b2, out);
}